// Round 5
// baseline (1183.626 us; speedup 1.0000x reference)
//
#include <hip/hip_runtime.h>
#include <math.h>
#include <stdint.h>

#define B_ROWS 4096
#define D_DIM  768
#define M_ROWS 100000
#define K_TOP  10

// ---------------- MFMA-path constants ----------------
#define KSTEPS 48          // 768 / 16
#define E32N   3125        // evidence 32-row tiles
#define B32N   128         // batch 32-row tiles
#define NGRP   16          // evidence groups
#define NBB    16          // batch blocks (256 rows each)
#define NITER_TOT 391      // ceil(3125/8)
#define CAND   12          // candidates kept per (row, group)
#define KCN    24          // k-chunks of 32 (24*32 = 768)
#define LTK    6           // per-lane top-k length

typedef _Float16 f16;
typedef _Float16 f16x8 __attribute__((ext_vector_type(8)));
typedef float   f32x16 __attribute__((ext_vector_type(16)));

// workspace layout (bytes)
#define XF_BYTES (128ull * 48 * 1024)
#define EF_OFF   XF_BYTES
#define EF_BYTES (3125ull * 48 * 1024)
#define CS_OFF   (EF_OFF + EF_BYTES)
#define CS_BYTES (4096ull * NGRP * CAND * 4)
#define CI_OFF   (CS_OFF + CS_BYTES)
#define CI_BYTES (4096ull * NGRP * CAND * 4)
#define WS_NEED  (CI_OFF + CI_BYTES)

// ---------------------------------------------------------------------------
// Convert fp32 [rows][768] -> f16 fragment-tiled [band32][ks48][lane64][j8].
// frag value (l,j) = src[band*32 + (l&31)][ks*16 + 8*(l>>5) + j]
// ---------------------------------------------------------------------------
__global__ __launch_bounds__(256) void convert_frag(
    const float* __restrict__ src, f16* __restrict__ dst, int nband)
{
  int tid  = blockIdx.x * 256 + threadIdx.x;
  int l    = tid & 63;
  int rest = tid >> 6;
  int ks   = rest % KSTEPS;
  int band = rest / KSTEPS;
  if (band >= nband) return;
  int row = band * 32 + (l & 31);
  int k0  = ks * 16 + 8 * (l >> 5);
  const float* s = src + (size_t)row * D_DIM + k0;
  float4 v0 = *(const float4*)s;
  float4 v1 = *(const float4*)(s + 4);
  f16x8 o;
  o[0] = (f16)v0.x; o[1] = (f16)v0.y; o[2] = (f16)v0.z; o[3] = (f16)v0.w;
  o[4] = (f16)v1.x; o[5] = (f16)v1.y; o[6] = (f16)v1.z; o[7] = (f16)v1.w;
  *(f16x8*)(dst + (((size_t)band * KSTEPS + ks) << 9) + l * 8) = o;
}

// sorted top-6 insert (descending), static-indexed
__device__ __forceinline__ void ins6(float (&ts)[LTK], int (&ti)[LTK],
                                     float s, int idx)
{
  ts[LTK - 1] = s; ti[LTK - 1] = idx;
#pragma unroll
  for (int q = LTK - 1; q > 0; --q) {
    if (ts[q] > ts[q - 1]) {
      float a = ts[q]; ts[q] = ts[q - 1]; ts[q - 1] = a;
      int   b = ti[q]; ti[q] = ti[q - 1]; ti[q - 1] = b;
    }
  }
}

__device__ __forceinline__ float max16(const f32x16& v)
{
  float a = fmaxf(fmaxf(v[0], v[1]), fmaxf(v[2], v[3]));
  float b = fmaxf(fmaxf(v[4], v[5]), fmaxf(v[6], v[7]));
  float c = fmaxf(fmaxf(v[8], v[9]), fmaxf(v[10], v[11]));
  float d = fmaxf(fmaxf(v[12], v[13]), fmaxf(v[14], v[15]));
  return fmaxf(fmaxf(a, b), fmaxf(c, d));
}

__device__ __forceinline__ void gll16(const f16* src, f16* dst)
{
  __builtin_amdgcn_global_load_lds(
      (const __attribute__((address_space(1))) void*)(uintptr_t)src,
      (__attribute__((address_space(3))) void*)(uint32_t)(uintptr_t)dst,
      16, 0, 0);
}

// ---------------------------------------------------------------------------
// GEMM + fused per-lane top-k.  8 waves = 2 evid-waves x 4 batch-waves.
// Per block-iteration j: 256 evid rows x 256 batch cols, K=768.
// K-pipeline: chunks of K=32 (32 KB: 16 frags E + 16 frags X), 4 LDS buffers,
// prefetch depth 3, counted vmcnt(8) per chunk (never 0 in steady state),
// one barrier per chunk; pipeline maintained across j iterations.
// ---------------------------------------------------------------------------
__global__ __launch_bounds__(512, 2) void gemm_topk(
    const f16* __restrict__ Ef, const f16* __restrict__ Xf,
    float* __restrict__ cs, int* __restrict__ ci)
{
  __shared__ f16 lds[4][16384];   // 4 x 32 KB

  const int t    = threadIdx.x;
  const int lane = t & 63;
  const int w    = t >> 6;      // 0..7
  const int ew   = w >> 2;      // 0..1  evid-wave
  const int bw   = w & 3;       // 0..3  batch-wave

  // XCD-aware remap: ids congruent mod 8 share an XCD.
  const int id = blockIdx.x;
  const int g  = (id & 7) + 8 * (id >> 7);        // evidence group 0..15
  const int bb = (id >> 3) & 15;                  // batch block 0..15
  const int niter = 24 + (g < (NITER_TOT - 16 * 24) ? 1 : 0);

  // wave-uniform staging roles: waves 0..3 stage E (tiles et=2w,2w+1),
  // waves 4..7 stage X (tiles bt=2(w-4),2(w-4)+1). 4 loads/wave/chunk.
  const bool isE = (w < 4);
  const f16* xs0 = Xf + ((size_t)(bb * 8 + 2 * (w - 4)) * KSTEPS) * 512;
  const f16* xs1 = Xf + ((size_t)(bb * 8 + 2 * (w - 4) + 1) * KSTEPS) * 512;
  // dst: buf frags: E tile et -> frags et*2+{0,1}; X tile bt -> 16+bt*2+{0,1}
  const uint32_t dbase = (isE ? (4 * w) * 512 : (16 + 4 * (w - 4)) * 512);

  auto STAGE = [&](int e32b, int kc, int bufi) {
    const f16 *s0, *s1;
    if (isE) {
      int ea = e32b + 2 * w;     if (ea > E32N - 1) ea = E32N - 1;
      int eb = e32b + 2 * w + 1; if (eb > E32N - 1) eb = E32N - 1;
      s0 = Ef + ((size_t)ea * KSTEPS + 2 * kc) * 512;
      s1 = Ef + ((size_t)eb * KSTEPS + 2 * kc) * 512;
    } else {
      s0 = xs0 + (size_t)(2 * kc) * 512;
      s1 = xs1 + (size_t)(2 * kc) * 512;
    }
    f16* dp = &lds[bufi][0] + dbase + lane * 8;
    gll16(s0 + lane * 8,       dp);
    gll16(s0 + lane * 8 + 512, dp + 512);
    gll16(s1 + lane * 8,       dp + 1024);
    gll16(s1 + lane * 8 + 512, dp + 1536);
  };

  float ts0[LTK], ts1[LTK]; int ti0[LTK], ti1[LTK];
#pragma unroll
  for (int q = 0; q < LTK; ++q) {
    ts0[q] = -INFINITY; ts1[q] = -INFINITY;
    ti0[q] = 0x7fffffff; ti1[q] = 0x7fffffff;
  }

  // prologue: stage chunks 0,1,2 of j=0
  STAGE(g * 8, 0, 0);
  STAGE(g * 8, 1, 1);
  STAGE(g * 8, 2, 2);

  for (int j = 0; j < niter; ++j) {
    const int e32base = (g + NGRP * j) * 8;
    const bool lastj = (j == niter - 1);

    f32x16 acc0[4], acc1[4];
#pragma unroll
    for (int e = 0; e < 4; ++e) {
#pragma unroll
      for (int q = 0; q < 16; ++q) { acc0[e][q] = 0.f; acc1[e][q] = 0.f; }
    }

#pragma unroll 1
    for (int kc = 0; kc < KCN; ++kc) {
      // counted waits: chunk kc's 4 loads landed; 8 stay in flight.
      if (!lastj || kc < KCN - 2) {
        asm volatile("s_waitcnt vmcnt(8)" ::: "memory");
      } else if (kc == KCN - 2) {
        asm volatile("s_waitcnt vmcnt(4)" ::: "memory");
      } else {
        asm volatile("s_waitcnt vmcnt(0)" ::: "memory");
      }
      __builtin_amdgcn_s_barrier();   // everyone's chunk-kc loads are in LDS

      // prefetch chunk kc+3 (buffer (kc+3)&3 was fully read in iter kc-1)
      if (kc < KCN - 3)      STAGE(e32base, kc + 3, (kc + 3) & 3);
      else if (!lastj)       STAGE(e32base + NGRP * 8, kc + 3 - KCN, (kc + 3) & 3);

      const f16* Lb = &lds[kc & 3][0];
#pragma unroll
      for (int u = 0; u < 2; ++u) {
        f16x8 a[4], b[2];
#pragma unroll
        for (int e = 0; e < 4; ++e)
          a[e] = *(const f16x8*)(Lb + (((ew * 4 + e) * 2 + u) << 9) + lane * 8);
#pragma unroll
        for (int x2 = 0; x2 < 2; ++x2)
          b[x2] = *(const f16x8*)(Lb + ((16 + (bw * 2 + x2) * 2 + u) << 9) + lane * 8);
        __builtin_amdgcn_s_setprio(1);
#pragma unroll
        for (int e = 0; e < 4; ++e) {
          acc0[e] = __builtin_amdgcn_mfma_f32_32x32x16_f16(a[e], b[0], acc0[e], 0, 0, 0);
          acc1[e] = __builtin_amdgcn_mfma_f32_32x32x16_f16(a[e], b[1], acc1[e], 0, 0, 0);
        }
        __builtin_amdgcn_s_setprio(0);
      }
    }

    // inserts, max-prefiltered per 16-value tile
    // C/D map: col=lane&31, row=(q&3)+8*(q>>2)+4*(lane>>5)
#pragma unroll
    for (int e = 0; e < 4; ++e) {
      const int ebase = e32base * 32 + (ew * 4 + e) * 32 + 4 * (lane >> 5);
      if (max16(acc0[e]) > ts0[LTK - 1]) {
#pragma unroll
        for (int q = 0; q < 16; ++q) {
          int eidx = ebase + (q & 3) + 8 * (q >> 2);
          float s = acc0[e][q];
          if (eidx < M_ROWS && s > ts0[LTK - 1]) ins6(ts0, ti0, s, eidx);
        }
      }
      if (max16(acc1[e]) > ts1[LTK - 1]) {
#pragma unroll
        for (int q = 0; q < 16; ++q) {
          int eidx = ebase + (q & 3) + 8 * (q >> 2);
          float s = acc1[e][q];
          if (eidx < M_ROWS && s > ts1[LTK - 1]) ins6(ts1, ti1, s, eidx);
        }
      }
    }
  }

  // ---- merge per batch-col: 4 lists (2 evid-waves x 2 lane-halves) -> top-12
  __syncthreads();
  float* ds = (float*)&lds[0][0];                      // 6144 floats (24 KB)
  int*   di = (int*)((char*)&lds[0][0] + 32 * 1024);
  {
    int half = lane >> 5, cl = lane & 31;
    int base0 = ((((ew * 2 + half) * 4 + bw) * 2 + 0) * 32 + cl) * LTK;
    int base1 = ((((ew * 2 + half) * 4 + bw) * 2 + 1) * 32 + cl) * LTK;
#pragma unroll
    for (int q = 0; q < LTK; ++q) {
      ds[base0 + q] = ts0[q]; di[base0 + q] = ti0[q];
      ds[base1 + q] = ts1[q]; di[base1 + q] = ti1[q];
    }
  }
  __syncthreads();
  if (t < 256) {
    int c = t; int bw2 = c >> 6, bt2 = (c >> 5) & 1, cl2 = c & 31;
    int hb[4];
#pragma unroll
    for (int u = 0; u < 4; ++u) {
      int ew2 = u >> 1, h2 = u & 1;
      hb[u] = ((((ew2 * 2 + h2) * 4 + bw2) * 2 + bt2) * 32 + cl2) * LTK;
    }
    const int row = bb * 256 + c;
    float* ocs = cs + ((size_t)row * NGRP + g) * CAND;
    int*   oci = ci + ((size_t)row * NGRP + g) * CAND;
    for (int o = 0; o < CAND; ++o) {
      float best = -INFINITY; int bidx = 0x7fffffff; int bu = 0, bq = 0;
#pragma unroll
      for (int u = 0; u < 4; ++u) {
        for (int q = 0; q < LTK; ++q) {
          float s = ds[hb[u] + q]; int id2 = di[hb[u] + q];
          if (s > best || (s == best && id2 < bidx)) { best = s; bidx = id2; bu = u; bq = q; }
        }
      }
      ds[hb[bu] + bq] = -INFINITY;
      ocs[o] = best; oci[o] = bidx;
    }
  }
}

// ---------------------------------------------------------------------------
// Final: per row merge 16*12=192 candidates -> approx top-16 -> fp64 rescore
// -> exact-ordered top-10 (absmax 0 in rounds 2-4).
// ---------------------------------------------------------------------------
__global__ __launch_bounds__(64) void final_merge(
    const float* __restrict__ x, const float* __restrict__ E,
    const float* __restrict__ cs, const int* __restrict__ ci,
    float* __restrict__ out)
{
  __shared__ float ls[192]; __shared__ int li[192];
  __shared__ int c16[16]; __shared__ double rs[16];
  const int row = blockIdx.x;
  const int lane = threadIdx.x;
  for (int q = lane; q < 192; q += 64) {
    ls[q] = cs[(size_t)row * 192 + q];
    li[q] = ci[(size_t)row * 192 + q];
  }
  __syncthreads();

  for (int o = 0; o < 16; ++o) {
    float bs = -INFINITY; int bi = 0x7fffffff; int bp = 0;
    for (int q = lane; q < 192; q += 64) {
      float s = ls[q];
      if (s > bs || (s == bs && li[q] < bi)) { bs = s; bi = li[q]; bp = q; }
    }
#pragma unroll
    for (int mk = 1; mk <= 32; mk <<= 1) {
      float qs = __shfl_xor(bs, mk, 64);
      int   qi = __shfl_xor(bi, mk, 64);
      int   qp = __shfl_xor(bp, mk, 64);
      if (qs > bs || (qs == bs && qi < bi)) { bs = qs; bi = qi; bp = qp; }
    }
    if (lane == 0) { c16[o] = bi; ls[bp] = -INFINITY; }
    __syncthreads();
  }

  {
    int cd = lane >> 2, p = lane & 3;
    int cid = c16[cd];
    const float* Er = E + (size_t)cid * D_DIM + p * 192;
    const float* Xr = x + (size_t)row * D_DIM + p * 192;
    double s = 0.0;
#pragma unroll 8
    for (int d = 0; d < 192; ++d) s += (double)Xr[d] * (double)Er[d];
    s += __shfl_xor(s, 1, 64);
    s += __shfl_xor(s, 2, 64);
    if (p == 0) rs[cd] = s;
  }
  __syncthreads();

  if (lane == 0) {
    for (int o = 0; o < K_TOP; ++o) {
      double bs = rs[0]; int bc = c16[0]; int b = 0;
      for (int q = 1; q < 16; ++q) {
        double v = rs[q]; int cq = c16[q];
        if (v > bs || (v == bs && cq < bc)) { bs = v; bc = cq; b = q; }
      }
      out[(size_t)row * K_TOP + o] = (float)bs;
      out[(size_t)B_ROWS * K_TOP + (size_t)row * K_TOP + o] = (float)bc;
      rs[b] = -1.0e300;
    }
  }
}

// ---------------------------------------------------------------------------
// Fallback (round-2 kernel) if ws_size is insufficient.
// ---------------------------------------------------------------------------
#define RB   16
#define GQ   64
#define MMF  4
#define NJ   391
#define NTF  1024
#define XPAD 772
#define DQ4  192

__global__ __launch_bounds__(NTF, 4) void retr_fused(
    const float* __restrict__ x, const float* __restrict__ E,
    float* __restrict__ out)
{
  __shared__ float smem[21248];
  const int t = threadIdx.x;
  const int r = t & 15;
  const int g = t >> 4;
  const int rb0 = blockIdx.x * RB;
  {
    const float4* xg = (const float4*)(x + (size_t)rb0 * D_DIM);
    for (int q = t; q < RB * DQ4; q += NTF) {
      int row = q / DQ4, c4 = q % DQ4;
      float4 v = xg[q];
      *(float4*)(smem + row * XPAD + c4 * 4) = v;
    }
  }
  __syncthreads();
  float ts[K_TOP]; int ti[K_TOP];
#pragma unroll
  for (int q = 0; q < K_TOP; ++q) { ts[q] = -INFINITY; ti[q] = 0x7fffffff; }
  const float4* xr4 = (const float4*)(smem + r * XPAD);
  for (int j = 0; j < NJ; ++j) {
    const int m0 = (g + (j << 6)) * MMF;
    const float4* ep[MMF];
#pragma unroll
    for (int mm = 0; mm < MMF; ++mm) {
      int ml = m0 + mm;
      int mc = (ml < M_ROWS) ? ml : (M_ROWS - 1);
      ep[mm] = (const float4*)(E + (size_t)mc * D_DIM);
    }
    float4 acc[MMF];
#pragma unroll
    for (int mm = 0; mm < MMF; ++mm) acc[mm] = make_float4(0.f, 0.f, 0.f, 0.f);
#pragma unroll 4
    for (int dq = 0; dq < DQ4; ++dq) {
      float4 xv = xr4[dq];
#pragma unroll
      for (int mm = 0; mm < MMF; ++mm) {
        float4 e = ep[mm][dq];
        acc[mm].x += e.x * xv.x; acc[mm].y += e.y * xv.y;
        acc[mm].z += e.z * xv.z; acc[mm].w += e.w * xv.w;
      }
    }
#pragma unroll
    for (int mm = 0; mm < MMF; ++mm) {
      int ml = m0 + mm;
      float s = (acc[mm].x + acc[mm].y) + (acc[mm].z + acc[mm].w);
      if (ml < M_ROWS && s > ts[K_TOP - 1]) {
        ts[K_TOP - 1] = s; ti[K_TOP - 1] = ml;
#pragma unroll
        for (int q = K_TOP - 1; q > 0; --q) {
          if (ts[q] > ts[q - 1]) {
            float tf = ts[q]; ts[q] = ts[q - 1]; ts[q - 1] = tf;
            int   tq = ti[q]; ti[q] = ti[q - 1]; ti[q - 1] = tq;
          }
        }
      }
    }
  }
  __syncthreads();
  float*  cs  = smem;
  int*    ci  = (int*)(smem + 10240);
  int*    cnd = (int*)(smem + 20480);
  double* rsd = (double*)(smem + 20736);
#pragma unroll
  for (int q = 0; q < K_TOP; ++q) {
    cs[(r * GQ + g) * K_TOP + q] = ts[q];
    ci[(r * GQ + g) * K_TOP + q] = ti[q];
  }
  __syncthreads();
  const int w = t >> 6;
  const int lane = t & 63;
  {
    float ms[K_TOP]; int mi[K_TOP];
#pragma unroll
    for (int q = 0; q < K_TOP; ++q) {
      ms[q] = cs[(w * GQ + lane) * K_TOP + q];
      mi[q] = ci[(w * GQ + lane) * K_TOP + q];
    }
    for (int o = 0; o < 16; ++o) {
      float hs = ms[0]; int hi = mi[0];
      float bs = hs;    int bi = hi;
#pragma unroll
      for (int mk = 1; mk <= 32; mk <<= 1) {
        float qs = __shfl_xor(bs, mk, 64);
        int   qi = __shfl_xor(bi, mk, 64);
        if (qs > bs || (qs == bs && qi < bi)) { bs = qs; bi = qi; }
      }
      bool win = (hs == bs) && (hi == bi);
      if (win) {
#pragma unroll
        for (int q = 0; q < K_TOP - 1; ++q) { ms[q] = ms[q + 1]; mi[q] = mi[q + 1]; }
        ms[K_TOP - 1] = -INFINITY; mi[K_TOP - 1] = 0x7fffffff;
      }
      if (lane == 0) cnd[w * 16 + o] = bi;
    }
  }
  __syncthreads();
  {
    int cand = lane >> 2, p = lane & 3;
    int cid = cnd[w * 16 + cand];
    const float* Er = E + (size_t)cid * D_DIM + p * 192;
    const float* Xr = x + (size_t)(rb0 + w) * D_DIM + p * 192;
    double s = 0.0;
#pragma unroll 8
    for (int d = 0; d < 192; ++d) s += (double)Xr[d] * (double)Er[d];
    s += __shfl_xor(s, 1, 64);
    s += __shfl_xor(s, 2, 64);
    if (p == 0) rsd[w * 16 + cand] = s;
  }
  __syncthreads();
  if (lane == 0) {
    const int row = rb0 + w;
    for (int o = 0; o < K_TOP; ++o) {
      double bsv = rsd[w * 16 + 0]; int bci = cnd[w * 16 + 0]; int b = 0;
      for (int q = 1; q < 16; ++q) {
        double v = rsd[w * 16 + q]; int c = cnd[w * 16 + q];
        if (v > bsv || (v == bsv && c < bci)) { bsv = v; bci = c; b = q; }
      }
      out[(size_t)row * K_TOP + o] = (float)bsv;
      out[(size_t)B_ROWS * K_TOP + (size_t)row * K_TOP + o] = (float)bci;
      rsd[w * 16 + b] = -1.0e300;
    }
  }
}

// ---------------------------------------------------------------------------
extern "C" void kernel_launch(void* const* d_in, const int* in_sizes, int n_in,
                              void* d_out, int out_size, void* d_ws, size_t ws_size,
                              hipStream_t stream) {
  const float* x = (const float*)d_in[0];
  const float* E = (const float*)d_in[1];
  float* out = (float*)d_out;

  if (ws_size < WS_NEED) {
    retr_fused<<<dim3(B_ROWS / RB), NTF, 0, stream>>>(x, E, out);
    return;
  }

  f16*   Xfp = (f16*)d_ws;
  f16*   Efp = (f16*)((char*)d_ws + EF_OFF);
  float* csp = (float*)((char*)d_ws + CS_OFF);
  int*   cip = (int*)((char*)d_ws + CI_OFF);

  convert_frag<<<dim3((B32N * KSTEPS * 64) / 256), 256, 0, stream>>>(x, Xfp, B32N);
  convert_frag<<<dim3((E32N * KSTEPS * 64) / 256), 256, 0, stream>>>(E, Efp, E32N);
  gemm_topk<<<dim3(NBB * NGRP), 512, 0, stream>>>(Efp, Xfp, csp, cip);
  final_merge<<<dim3(B_ROWS), 64, 0, stream>>>(x, E, csp, cip, out);
}